// Round 4
// baseline (198.225 us; speedup 1.0000x reference)
//
#include <hip/hip_runtime.h>

// x: (8, 160, 1024, 1) f32 ; W: (1, 7, 1, 32) f32
// y[n,h,w,c] = sum_k x[n,h,w+k-3] * W[k,c]   (SAME pad along w)
// per (n,w,c): m1 = max_h y, m2 = 2nd max, am = argmax_h
// out[n,h,w,c] = y[n,h,w,c] + (h==am ? m2 : m1)
//
// R4: LDS-issue-bound fix. 4 w/thread, all LDS reads as aligned float4
//     (3x ds_read_b128 per h per thread -> 0.75 LDS instr/output vs 7).
//     256 blocks (32c x 8wt threads, 32-w tile), 1 wave/SIMD, ILP from
//     4 parallel conv chains + unroll 2.

#define BLOCK 256
#define WTILE 32
#define LDSW  40            // row stride: 160 B, 16B-aligned rows

__global__ __launch_bounds__(BLOCK)
void pcc_kernel(const float* __restrict__ x,
                const float* __restrict__ Wf,
                float* __restrict__ out) {
    __shared__ __align__(16) float xs[160][LDSW];   // 25.6 KB

    const int n  = blockIdx.x >> 5;      // 32 w-tiles per n
    const int wt = blockIdx.x & 31;
    const int w0 = wt * WTILE;
    const int tid = threadIdx.x;

    // ---- stage x[n, 0:160, w0-4 .. w0+35] into LDS (zero-padded) ----
    // col j <-> global w = w0 - 4 + j
    const float* xn = x + (size_t)n * 160 * 1024;
    for (int idx = tid; idx < 160 * LDSW; idx += BLOCK) {
        int row = idx / LDSW;
        int col = idx - row * LDSW;
        int gw  = w0 - 4 + col;
        float v = 0.f;
        if (gw >= 0 && gw < 1024) v = xn[row * 1024 + gw];
        xs[row][col] = v;
    }
    __syncthreads();

    const int c = tid & 31;              // channel 0..31
    const int t = tid >> 5;              // w-group 0..7 -> w = w0+4t+k, k=0..3

    float wg[7];
#pragma unroll
    for (int k = 0; k < 7; ++k) wg[k] = Wf[k * 32 + c];

    // window for outputs k=0..3: taps at cols 4t+1 .. 4t+10
    // read f[0..11] = cols 4t .. 4t+11 as 3 aligned float4
    // y_k = sum_j f[k+1+j] * wg[j]

    float m1[4], m2[4];
    int   am[4];
#pragma unroll
    for (int k = 0; k < 4; ++k) { m1[k] = -INFINITY; m2[k] = -INFINITY; am[k] = 0; }

    // ---- pass 1: top-2 + argmax over h ----
#pragma unroll 2
    for (int h = 0; h < 160; ++h) {
        const float* row = &xs[h][4 * t];
        float4 A = *reinterpret_cast<const float4*>(row);
        float4 B = *reinterpret_cast<const float4*>(row + 4);
        float4 C = *reinterpret_cast<const float4*>(row + 8);
        float f[12] = {A.x, A.y, A.z, A.w, B.x, B.y, B.z, B.w, C.x, C.y, C.z, C.w};
        float y[4];
#pragma unroll
        for (int k = 0; k < 4; ++k) {
            float acc = 0.f;
#pragma unroll
            for (int j = 0; j < 7; ++j) acc = fmaf(f[k + 1 + j], wg[j], acc);
            y[k] = acc;
        }
#pragma unroll
        for (int k = 0; k < 4; ++k) {
            bool g = y[k] > m1[k];
            m2[k] = g ? m1[k] : fmaxf(m2[k], y[k]);
            m1[k] = g ? y[k]  : m1[k];
            am[k] = g ? h     : am[k];
        }
    }

    // ---- pass 2: recompute conv, add max-other, store ----
    float* obase = out + ((size_t)(n * 160) * 1024 + (w0 + 4 * t)) * 32 + c;
#pragma unroll 2
    for (int h = 0; h < 160; ++h) {
        const float* row = &xs[h][4 * t];
        float4 A = *reinterpret_cast<const float4*>(row);
        float4 B = *reinterpret_cast<const float4*>(row + 4);
        float4 C = *reinterpret_cast<const float4*>(row + 8);
        float f[12] = {A.x, A.y, A.z, A.w, B.x, B.y, B.z, B.w, C.x, C.y, C.z, C.w};
        float* orow = obase + (size_t)h * 1024 * 32;
#pragma unroll
        for (int k = 0; k < 4; ++k) {
            float acc = 0.f;
#pragma unroll
            for (int j = 0; j < 7; ++j) acc = fmaf(f[k + 1 + j], wg[j], acc);
            orow[k * 32] = acc + (h == am[k] ? m2[k] : m1[k]);
        }
    }
}

extern "C" void kernel_launch(void* const* d_in, const int* in_sizes, int n_in,
                              void* d_out, int out_size, void* d_ws, size_t ws_size,
                              hipStream_t stream) {
    const float* x  = (const float*)d_in[0];   // 8*160*1024
    const float* Wf = (const float*)d_in[1];   // 7*32
    float* out = (float*)d_out;                // 8*160*1024*32
    dim3 grid(8 * (1024 / WTILE));             // 256 blocks
    dim3 block(BLOCK);
    pcc_kernel<<<grid, block, 0, stream>>>(x, Wf, out);
}